// Round 9
// baseline (173.699 us; speedup 1.0000x reference)
//
#include <hip/hip_runtime.h>

#define NHALF 4096
#define NROWS 8192
#define D 512
#define BM 128                 // A-tile rows
#define BN 256                 // B-strip rows (2 j-tiles of 128)
#define BK 64
#define NSTRIP 1056            // sum over bi of (32 - bi/2); divisible by 8
#define CONV_BLOCKS 128
#define LOG2E 1.4426950408889634

typedef __bf16 bf16x8 __attribute__((ext_vector_type(8)));
typedef float  f32x4  __attribute__((ext_vector_type(4)));

__device__ __forceinline__ const float* row_ptr(const float* __restrict__ src,
                                                const float* __restrict__ tgt, int r) {
    return (r < NHALF) ? (src + (size_t)r * D) : (tgt + (size_t)(r - NHALF) * D);
}

// --- Pass A: fused convert fp32->bf16 + rowsq + colsum + sumsq + (last block) bandwidth ---
__global__ __launch_bounds__(256)
void conv_stats(const float* __restrict__ src, const float* __restrict__ tgt,
                __bf16* __restrict__ tot, float* __restrict__ sq,
                float* __restrict__ colsum, double* __restrict__ sumsq,
                unsigned* __restrict__ ticket, float* __restrict__ c2p_out) {
    __shared__ float cs_lds[4][512];
    __shared__ float wssq[4];
    __shared__ int lastFlag;
    __shared__ double red[256];
    int t = threadIdx.x, l = t & 63, w = t >> 6;
    int rbase = blockIdx.x * 64 + w * 16;

    float cs[8] = {0.f, 0.f, 0.f, 0.f, 0.f, 0.f, 0.f, 0.f};
    float ssq = 0.f;

    for (int rr = 0; rr < 16; ++rr) {
        int r = rbase + rr;
        const float* p = row_ptr(src, tgt, r) + l * 8;
        float4 v0 = *(const float4*)p;
        float4 v1 = *(const float4*)(p + 4);
        bf16x8 o;
        o[0] = (__bf16)v0.x; o[1] = (__bf16)v0.y; o[2] = (__bf16)v0.z; o[3] = (__bf16)v0.w;
        o[4] = (__bf16)v1.x; o[5] = (__bf16)v1.y; o[6] = (__bf16)v1.z; o[7] = (__bf16)v1.w;
        *(bf16x8*)&tot[(size_t)r * D + l * 8] = o;
        float s8 = v0.x*v0.x + v0.y*v0.y + v0.z*v0.z + v0.w*v0.w
                 + v1.x*v1.x + v1.y*v1.y + v1.z*v1.z + v1.w*v1.w;
        ssq += s8;
        cs[0] += v0.x; cs[1] += v0.y; cs[2] += v0.z; cs[3] += v0.w;
        cs[4] += v1.x; cs[5] += v1.y; cs[6] += v1.z; cs[7] += v1.w;
        float rsum = s8;
        for (int off = 32; off > 0; off >>= 1) rsum += __shfl_down(rsum, off);
        if (l == 0) sq[r] = rsum;
    }
#pragma unroll
    for (int j = 0; j < 8; ++j) cs_lds[w][l * 8 + j] = cs[j];
    for (int off = 32; off > 0; off >>= 1) ssq += __shfl_down(ssq, off);
    if (l == 0) wssq[w] = ssq;
    __syncthreads();
    int c0 = t * 2;
    float a = cs_lds[0][c0] + cs_lds[1][c0] + cs_lds[2][c0] + cs_lds[3][c0];
    float b = cs_lds[0][c0+1] + cs_lds[1][c0+1] + cs_lds[2][c0+1] + cs_lds[3][c0+1];
    atomicAdd(&colsum[c0], a);
    atomicAdd(&colsum[c0 + 1], b);
    if (t == 0) atomicAdd(sumsq, (double)(wssq[0] + wssq[1] + wssq[2] + wssq[3]));
    __syncthreads();

    if (t == 0) {
        __threadfence();
        unsigned old = atomicAdd(ticket, 1u);
        lastFlag = (old == CONV_BLOCKS - 1) ? 1 : 0;
    }
    __syncthreads();
    if (lastFlag) {
        float ca = atomicAdd(&colsum[t], 0.f);
        float cb = atomicAdd(&colsum[t + 256], 0.f);
        red[t] = (double)ca * ca + (double)cb * cb;
        __syncthreads();
        for (int s = 128; s > 0; s >>= 1) {
            if (t < s) red[t] += red[t + s];
            __syncthreads();
        }
        if (t == 0) {
            double ssqd = atomicAdd(sumsq, 0.0);
            double m = (double)NROWS;
            double sumL2 = 2.0 * m * ssqd - 2.0 * red[0];
            double bw = sumL2 / (m * m - m) / 4.0;
            c2p_out[0] = (float)(LOG2E / (16.0 * bw));
        }
    }
}

// --- Pass B: 128x256 j-strip MFMA kernel, 4 waves, single-buffer planar LDS ---
__global__ __launch_bounds__(256)
void mmd_main(const __bf16* __restrict__ tot, const float* __restrict__ sq,
              const float* __restrict__ c2p_p, double* __restrict__ S,
              unsigned* __restrict__ ticket, float* __restrict__ out) {
    int b = blockIdx.x;
    int p = (b & 7) * (NSTRIP / 8) + (b >> 3);   // XCD-chunked (1056 % 8 == 0, bijective)
    // p -> (q, r): row-pair q has 2*(32-q) entries; C(q) = q*(65-q)
    int q = (int)((65.f - sqrtf(65.f * 65.f - 4.f * (float)p)) * 0.5f);
    if (q < 0) q = 0;
    while (q > 0 && q * (65 - q) > p) --q;
    while ((q + 1) * (64 - q) <= p) ++q;
    int r = p - q * (65 - q);
    int half = 32 - q;
    int bi = 2 * q + (r >= half ? 1 : 0);        // A-tile index (128-row tiles, 0..63)
    int s  = q + (r >= half ? r - half : r);     // B-strip index (256-row strips, 0..31)

    // planar LDS: [plane 0..7][row][8 bf16] — conflict-free for gload_lds and frag reads
    __shared__ __align__(16) __bf16 As[8][BM][8];   // 16 KB
    __shared__ __align__(16) __bf16 Bs[8][BN][8];   // 32 KB
    __shared__ float wsum[4];

    int t = threadIdx.x, l = t & 63, w = t >> 6;
    int r0 = l & 15, kg = l >> 4;

    const __bf16* ab = tot + (size_t)(bi * BM) * D;
    const __bf16* bb = tot + (size_t)(s * BN) * D;

    f32x4 acc[8][4];
#pragma unroll
    for (int i = 0; i < 8; ++i)
#pragma unroll
        for (int j = 0; j < 4; ++j)
            acc[i][j] = (f32x4){0.f, 0.f, 0.f, 0.f};

    for (int kt = 0; kt < 8; ++kt) {
        __syncthreads();   // previous iteration's LDS reads done
        // A: 1024 granules (plane*128+row), 4 per thread
#pragma unroll
        for (int i = 0; i < 4; ++i) {
            int g = i * 256 + t;
            int plane = g >> 7, row = g & 127;
            __builtin_amdgcn_global_load_lds(
                (const __attribute__((address_space(1))) void*)(ab + (size_t)row * D + kt * BK + plane * 8),
                (__attribute__((address_space(3))) void*)(&As[0][0][0] + g * 8),
                16, 0, 0);
        }
        // B: 2048 granules (plane*256+row), 8 per thread
#pragma unroll
        for (int i = 0; i < 8; ++i) {
            int g = i * 256 + t;
            int plane = g >> 8, row = g & 255;
            __builtin_amdgcn_global_load_lds(
                (const __attribute__((address_space(1))) void*)(bb + (size_t)row * D + kt * BK + plane * 8),
                (__attribute__((address_space(3))) void*)(&Bs[0][0][0] + g * 8),
                16, 0, 0);
        }
        __syncthreads();   // drains vmcnt(0): tile ready

#pragma unroll
        for (int ks = 0; ks < 2; ++ks) {
            bf16x8 af[8], bfr[4];
#pragma unroll
            for (int fi = 0; fi < 8; ++fi)
                af[fi] = *(const bf16x8*)&As[ks * 4 + kg][fi * 16 + r0][0];
#pragma unroll
            for (int fj = 0; fj < 4; ++fj)
                bfr[fj] = *(const bf16x8*)&Bs[ks * 4 + kg][w * 64 + fj * 16 + r0][0];
#pragma unroll
            for (int fi = 0; fi < 8; ++fi)
#pragma unroll
                for (int fj = 0; fj < 4; ++fj)
                    acc[fi][fj] = __builtin_amdgcn_mfma_f32_16x16x32_bf16(af[fi], bfr[fj], acc[fi][fj], 0, 0, 0);
        }
    }

    // Epilogue: per-wave j-tile coef; 5-kernel sum via exp2 (1 exp + 4 squarings)
    float c2p = c2p_p[0];
    float tc2 = c2p + c2p;
    int bj = 2 * s + (w >> 1);          // this wave's j-tile (128-row tiles)
    float coef;
    if (bj < bi) coef = 0.f;            // lower-tri tile in a diagonal strip: skip
    else {
        coef = (bj == bi) ? 1.f : 2.f;
        coef *= ((bi < 32) == (bj < 32)) ? 1.f : -1.f;
    }

    int jb = s * BN + w * 64 + r0;
    float cj[4];
#pragma unroll
    for (int fj = 0; fj < 4; ++fj) cj[fj] = c2p * sq[jb + fj * 16];
    int ib = bi * BM + (l >> 4) * 4;

    float local = 0.f;
#pragma unroll
    for (int fi = 0; fi < 8; ++fi) {
        float ci[4];
#pragma unroll
        for (int j = 0; j < 4; ++j) ci[j] = c2p * sq[ib + fi * 16 + j];
#pragma unroll
        for (int fj = 0; fj < 4; ++fj) {
#pragma unroll
            for (int j = 0; j < 4; ++j) {
                float arg = fmaf(acc[fi][fj][j], tc2, -(ci[j] + cj[fj]));
                float u = exp2f(arg);          // e^{-L2/16bw}
                float ks2 = u;
                u *= u; ks2 += u;              // /8bw
                u *= u; ks2 += u;              // /4bw
                u *= u; ks2 += u;              // /2bw
                u *= u; ks2 += u;              // /bw
                local += ks2;
            }
        }
    }
    local *= coef;

    for (int off = 32; off > 0; off >>= 1) local += __shfl_down(local, off);
    if (l == 0) wsum[w] = local;
    __syncthreads();
    if (t == 0) {
        float bsum = wsum[0] + wsum[1] + wsum[2] + wsum[3];
        atomicAdd(S, (double)bsum);
        __threadfence();
        unsigned old = atomicAdd(ticket, 1u);
        if (old == NSTRIP - 1) {
            double Sv = atomicAdd(S, 0.0);
            out[0] = (float)(Sv / ((double)NHALF * (double)NHALF));
        }
    }
}

extern "C" void kernel_launch(void* const* d_in, const int* in_sizes, int n_in,
                              void* d_out, int out_size, void* d_ws, size_t ws_size,
                              hipStream_t stream) {
    const float* src = (const float*)d_in[0];
    const float* tgt = (const float*)d_in[1];
    float* out = (float*)d_out;
    char* ws = (char*)d_ws;

    __bf16*   tot     = (__bf16*)ws;                       // 8 MB
    float*    sq      = (float*)(ws + 8388608);            // 32768 B
    float*    colsum  = (float*)(ws + 8388608 + 32768);    // 2048 B
    double*   sumsq   = (double*)(ws + 8388608 + 34816);   // 8 B
    double*   S       = (double*)(ws + 8388608 + 34824);   // 8 B
    unsigned* ticket1 = (unsigned*)(ws + 8388608 + 34832); // 4 B
    unsigned* ticket2 = (unsigned*)(ws + 8388608 + 34836); // 4 B
    float*    c2p     = (float*)(ws + 8388608 + 34840);    // 4 B

    hipMemsetAsync(ws + 8388608 + 32768, 0, 2072, stream);

    conv_stats<<<CONV_BLOCKS, 256, 0, stream>>>(src, tgt, tot, sq, colsum, sumsq, ticket1, c2p);
    mmd_main<<<NSTRIP, 256, 0, stream>>>(tot, sq, c2p, S, ticket2, out);
}

// Round 10
// 162.341 us; speedup vs baseline: 1.0700x; 1.0700x over previous
//
#include <hip/hip_runtime.h>

#define NHALF 4096
#define NROWS 8192
#define D 512
#define BM 128
#define BK 64
#define NB (NROWS / BM)            // 64
#define NTRI (NB * (NB + 1) / 2)   // 2080 (divisible by 8)
#define CONV_BLOCKS 128
#define LOG2E 1.4426950408889634

typedef __bf16 bf16x8 __attribute__((ext_vector_type(8)));
typedef float  f32x4  __attribute__((ext_vector_type(4)));

__device__ __forceinline__ const float* row_ptr(const float* __restrict__ src,
                                                const float* __restrict__ tgt, int r) {
    return (r < NHALF) ? (src + (size_t)r * D) : (tgt + (size_t)(r - NHALF) * D);
}

// --- Pass A: fused convert fp32->bf16 + rowsq + colsum + sumsq + (last block) bandwidth ---
__global__ __launch_bounds__(256)
void conv_stats(const float* __restrict__ src, const float* __restrict__ tgt,
                __bf16* __restrict__ tot, float* __restrict__ sq,
                float* __restrict__ colsum, double* __restrict__ sumsq,
                unsigned* __restrict__ ticket, float* __restrict__ c2p_out) {
    __shared__ float cs_lds[4][512];
    __shared__ float wssq[4];
    __shared__ int lastFlag;
    __shared__ double red[256];
    int t = threadIdx.x, l = t & 63, w = t >> 6;
    int rbase = blockIdx.x * 64 + w * 16;

    float cs[8] = {0.f, 0.f, 0.f, 0.f, 0.f, 0.f, 0.f, 0.f};
    float ssq = 0.f;

    for (int rr = 0; rr < 16; ++rr) {
        int r = rbase + rr;
        const float* p = row_ptr(src, tgt, r) + l * 8;
        float4 v0 = *(const float4*)p;
        float4 v1 = *(const float4*)(p + 4);
        bf16x8 o;
        o[0] = (__bf16)v0.x; o[1] = (__bf16)v0.y; o[2] = (__bf16)v0.z; o[3] = (__bf16)v0.w;
        o[4] = (__bf16)v1.x; o[5] = (__bf16)v1.y; o[6] = (__bf16)v1.z; o[7] = (__bf16)v1.w;
        *(bf16x8*)&tot[(size_t)r * D + l * 8] = o;
        float s8 = v0.x*v0.x + v0.y*v0.y + v0.z*v0.z + v0.w*v0.w
                 + v1.x*v1.x + v1.y*v1.y + v1.z*v1.z + v1.w*v1.w;
        ssq += s8;
        cs[0] += v0.x; cs[1] += v0.y; cs[2] += v0.z; cs[3] += v0.w;
        cs[4] += v1.x; cs[5] += v1.y; cs[6] += v1.z; cs[7] += v1.w;
        float rsum = s8;
        for (int off = 32; off > 0; off >>= 1) rsum += __shfl_down(rsum, off);
        if (l == 0) sq[r] = rsum;
    }
#pragma unroll
    for (int j = 0; j < 8; ++j) cs_lds[w][l * 8 + j] = cs[j];
    for (int off = 32; off > 0; off >>= 1) ssq += __shfl_down(ssq, off);
    if (l == 0) wssq[w] = ssq;
    __syncthreads();
    int c0 = t * 2;
    float a = cs_lds[0][c0] + cs_lds[1][c0] + cs_lds[2][c0] + cs_lds[3][c0];
    float b = cs_lds[0][c0+1] + cs_lds[1][c0+1] + cs_lds[2][c0+1] + cs_lds[3][c0+1];
    atomicAdd(&colsum[c0], a);
    atomicAdd(&colsum[c0 + 1], b);
    if (t == 0) atomicAdd(sumsq, (double)(wssq[0] + wssq[1] + wssq[2] + wssq[3]));
    __syncthreads();

    if (t == 0) {
        __threadfence();
        unsigned old = atomicAdd(ticket, 1u);
        lastFlag = (old == CONV_BLOCKS - 1) ? 1 : 0;
    }
    __syncthreads();
    if (lastFlag) {
        float ca = atomicAdd(&colsum[t], 0.f);
        float cb = atomicAdd(&colsum[t + 256], 0.f);
        red[t] = (double)ca * ca + (double)cb * cb;
        __syncthreads();
        for (int s = 128; s > 0; s >>= 1) {
            if (t < s) red[t] += red[t + s];
            __syncthreads();
        }
        if (t == 0) {
            double ssqd = atomicAdd(sumsq, 0.0);
            double m = (double)NROWS;
            double sumL2 = 2.0 * m * ssqd - 2.0 * red[0];
            double bw = sumL2 / (m * m - m) / 4.0;
            c2p_out[0] = (float)(LOG2E / (16.0 * bw));
        }
    }
}

// --- Pass B: 128x128 tile, 8 waves, dbuf LDS, stage-early pipeline ---
__global__ __launch_bounds__(512, 4)
void mmd_main(const __bf16* __restrict__ tot, const float* __restrict__ sq,
              const float* __restrict__ c2p_p, double* __restrict__ S,
              unsigned* __restrict__ ticket, float* __restrict__ out) {
    int b = blockIdx.x;
    int ti = (b & 7) * (NTRI / 8) + (b >> 3);   // XCD swizzle (2080 % 8 == 0, bijective)
    int bi = (int)(64.5f - sqrtf(64.5f * 64.5f - 2.0f * (float)ti));
    if (bi < 0) bi = 0;
    while (bi > 0 && bi * NB - bi * (bi - 1) / 2 > ti) --bi;
    while ((bi + 1) * NB - (bi + 1) * bi / 2 <= ti) ++bi;
    int bj = bi + (ti - (bi * NB - bi * (bi - 1) / 2));

    // planar dbuf LDS: [sel][plane 0..7][row 0..127][8 bf16]; 16 KB per tile-buffer
    __shared__ __align__(16) __bf16 As[2][8][BM][8];
    __shared__ __align__(16) __bf16 Bs[2][8][BM][8];
    __shared__ float wsum[8];

    int t = threadIdx.x, l = t & 63, w = t >> 6;
    int wr = w >> 2, wc = w & 3;       // 2x4 wave grid; per-wave 64x32 output
    int r0 = l & 15, kg = l >> 4;

    const __bf16* ab = tot + (size_t)(bi * BM) * D;
    const __bf16* bb = tot + (size_t)(bj * BM) * D;

    auto stage = [&](int sel, int kt) {
#pragma unroll
        for (int i = 0; i < 2; ++i) {
            int g = i * 512 + t;            // 0..1023 = plane*128 + row
            int plane = g >> 7, row = g & 127;
            __builtin_amdgcn_global_load_lds(
                (const __attribute__((address_space(1))) void*)(ab + (size_t)row * D + kt * BK + plane * 8),
                (__attribute__((address_space(3))) void*)(&As[sel][0][0][0] + g * 8),
                16, 0, 0);
            __builtin_amdgcn_global_load_lds(
                (const __attribute__((address_space(1))) void*)(bb + (size_t)row * D + kt * BK + plane * 8),
                (__attribute__((address_space(3))) void*)(&Bs[sel][0][0][0] + g * 8),
                16, 0, 0);
        }
    };

    f32x4 acc[4][2];
#pragma unroll
    for (int i = 0; i < 4; ++i)
#pragma unroll
        for (int j = 0; j < 2; ++j)
            acc[i][j] = (f32x4){0.f, 0.f, 0.f, 0.f};

    stage(0, 0);
    __syncthreads();   // prologue drain

    for (int kt = 0; kt < 8; ++kt) {
        int cur = kt & 1;
        if (kt < 7) stage(cur ^ 1, kt + 1);   // issue next-tile loads before compute
#pragma unroll
        for (int ks = 0; ks < 2; ++ks) {
            bf16x8 af[4], bfr[2];
#pragma unroll
            for (int fi = 0; fi < 4; ++fi)
                af[fi] = *(const bf16x8*)&As[cur][ks * 4 + kg][wr * 64 + fi * 16 + r0][0];
#pragma unroll
            for (int fj = 0; fj < 2; ++fj)
                bfr[fj] = *(const bf16x8*)&Bs[cur][ks * 4 + kg][wc * 32 + fj * 16 + r0][0];
#pragma unroll
            for (int fi = 0; fi < 4; ++fi)
#pragma unroll
                for (int fj = 0; fj < 2; ++fj)
                    acc[fi][fj] = __builtin_amdgcn_mfma_f32_16x16x32_bf16(af[fi], bfr[fj], acc[fi][fj], 0, 0, 0);
        }
        __syncthreads();   // drains vmcnt(0): next-stage latency hidden under this tile's MFMA
    }

    // Epilogue: L2 -> 5-kernel sum via exp2 (1 exp + 4 squarings)
    float c2p = c2p_p[0];
    float tc2 = c2p + c2p;
    float coef = ((bi == bj) ? 1.f : 2.f) * (((bi < NB / 2) == (bj < NB / 2)) ? 1.f : -1.f);

    int jb = bj * BM + wc * 32 + r0;
    float cj[2];
#pragma unroll
    for (int fj = 0; fj < 2; ++fj) cj[fj] = c2p * sq[jb + fj * 16];
    int ib = bi * BM + wr * 64 + (l >> 4) * 4;

    float local = 0.f;
#pragma unroll
    for (int fi = 0; fi < 4; ++fi) {
        float ci[4];
#pragma unroll
        for (int j = 0; j < 4; ++j) ci[j] = c2p * sq[ib + fi * 16 + j];
#pragma unroll
        for (int fj = 0; fj < 2; ++fj) {
#pragma unroll
            for (int j = 0; j < 4; ++j) {
                float arg = fmaf(acc[fi][fj][j], tc2, -(ci[j] + cj[fj]));
                float u = exp2f(arg);          // e^{-L2/16bw}
                float ks2 = u;
                u *= u; ks2 += u;              // /8bw
                u *= u; ks2 += u;              // /4bw
                u *= u; ks2 += u;              // /2bw
                u *= u; ks2 += u;              // /bw
                local += ks2;
            }
        }
    }
    local *= coef;

    for (int off = 32; off > 0; off >>= 1) local += __shfl_down(local, off);
    if (l == 0) wsum[w] = local;
    __syncthreads();
    if (t == 0) {
        float bsum = wsum[0] + wsum[1] + wsum[2] + wsum[3]
                   + wsum[4] + wsum[5] + wsum[6] + wsum[7];
        atomicAdd(S, (double)bsum);
        __threadfence();
        unsigned old = atomicAdd(ticket, 1u);
        if (old == NTRI - 1) {
            double Sv = atomicAdd(S, 0.0);
            out[0] = (float)(Sv / ((double)NHALF * (double)NHALF));
        }
    }
}

extern "C" void kernel_launch(void* const* d_in, const int* in_sizes, int n_in,
                              void* d_out, int out_size, void* d_ws, size_t ws_size,
                              hipStream_t stream) {
    const float* src = (const float*)d_in[0];
    const float* tgt = (const float*)d_in[1];
    float* out = (float*)d_out;
    char* ws = (char*)d_ws;

    __bf16*   tot     = (__bf16*)ws;                       // 8 MB
    float*    sq      = (float*)(ws + 8388608);            // 32768 B
    float*    colsum  = (float*)(ws + 8388608 + 32768);    // 2048 B
    double*   sumsq   = (double*)(ws + 8388608 + 34816);   // 8 B
    double*   S       = (double*)(ws + 8388608 + 34824);   // 8 B
    unsigned* ticket1 = (unsigned*)(ws + 8388608 + 34832); // 4 B
    unsigned* ticket2 = (unsigned*)(ws + 8388608 + 34836); // 4 B
    float*    c2p     = (float*)(ws + 8388608 + 34840);    // 4 B

    hipMemsetAsync(ws + 8388608 + 32768, 0, 2072, stream);

    conv_stats<<<CONV_BLOCKS, 256, 0, stream>>>(src, tgt, tot, sq, colsum, sumsq, ticket1, c2p);
    mmd_main<<<NTRI, 512, 0, stream>>>(tot, sq, c2p, S, ticket2, out);
}